// Round 1
// baseline (334.980 us; speedup 1.0000x reference)
//
#include <hip/hip_runtime.h>
#include <math.h>

#define NB 8
#define NCH 30
#define LL 16384
#define N1 6000
#define N2 4914
#define NCLS 5
#define KLIM 8192
#define ATT_K 13
#define APAD 6

__device__ __forceinline__ unsigned fkey(float f) {
  unsigned u = __float_as_uint(f);
  unsigned m = (unsigned)(((int)u) >> 31) | 0x80000000u;
  return u ^ m;  // order-preserving float->uint
}
__device__ __forceinline__ float sigmoidf(float x) { return 1.f / (1.f + expf(-x)); }

// ---- K1: per-(b,c) mean pool over HxH = 16384 ----
__global__ void k_pool(const float* __restrict__ adj, float* __restrict__ pooled) {
  int bc = blockIdx.x;                       // 0..239
  const float* p = adj + (size_t)bc * LL;
  int tid = threadIdx.x;
  float s = 0.f;
  #pragma unroll
  for (int it = 0; it < LL / (256 * 4); ++it) {
    float4 v = *(const float4*)(p + it * 1024 + tid * 4);
    s += v.x + v.y + v.z + v.w;
  }
  #pragma unroll
  for (int m = 1; m < 64; m <<= 1) s += __shfl_xor(s, m);
  __shared__ float red[4];
  if ((tid & 63) == 0) red[tid >> 6] = s;
  __syncthreads();
  if (tid == 0) pooled[bc] = (red[0] + red[1] + red[2] + red[3]) * (1.f / (float)LL);
}

// ---- K2: ECA conv(k=3,pad=1) + sigmoid; writes scale and band_score output ----
__global__ void k_eca(const float* __restrict__ pooled, const float* __restrict__ w,
                      float* __restrict__ scale, float* __restrict__ band_out) {
  int t = threadIdx.x;
  if (t < NB * NCH) {
    int b = t / NCH, c = t % NCH;
    const float* p = pooled + b * NCH;
    float s = w[1] * p[c];
    if (c > 0)       s += w[0] * p[c - 1];
    if (c < NCH - 1) s += w[2] * p[c + 1];
    float sc = sigmoidf(s);
    scale[t] = sc;
    band_out[t] = sc;
  }
}

// ---- K3: y[b,j] = sum_c adj[b,c,j]*scale[b,c]; per-block partial min/max ----
__global__ void k_wsum(const float* __restrict__ adj, const float* __restrict__ scale,
                       float* __restrict__ y, float* __restrict__ pmm) {
  int blk = blockIdx.x;                       // b*16 + tile
  int b = blk >> 4, tile = blk & 15;
  int tid = threadIdx.x;
  __shared__ float sc[NCH];
  if (tid < NCH) sc[tid] = scale[b * NCH + tid];
  __syncthreads();
  int j = tile * 1024 + tid * 4;
  const float* base = adj + (size_t)b * NCH * LL + j;
  float4 acc = {0.f, 0.f, 0.f, 0.f};
  #pragma unroll
  for (int c = 0; c < NCH; ++c) {
    float4 v = *(const float4*)(base + (size_t)c * LL);
    float s = sc[c];
    acc.x += v.x * s; acc.y += v.y * s; acc.z += v.z * s; acc.w += v.w * s;
  }
  *(float4*)(y + b * LL + j) = acc;
  float mn = fminf(fminf(acc.x, acc.y), fminf(acc.z, acc.w));
  float mx = fmaxf(fmaxf(acc.x, acc.y), fmaxf(acc.z, acc.w));
  #pragma unroll
  for (int m = 1; m < 64; m <<= 1) {
    mn = fminf(mn, __shfl_xor(mn, m));
    mx = fmaxf(mx, __shfl_xor(mx, m));
  }
  __shared__ float wmn[4], wmx[4];
  if ((tid & 63) == 0) { wmn[tid >> 6] = mn; wmx[tid >> 6] = mx; }
  __syncthreads();
  if (tid == 0) {
    mn = fminf(fminf(wmn[0], wmn[1]), fminf(wmn[2], wmn[3]));
    mx = fmaxf(fmaxf(wmx[0], wmx[1]), fmaxf(wmx[2], wmx[3]));
    pmm[blk * 2 + 0] = mn; pmm[blk * 2 + 1] = mx;
  }
}

// ---- K4: finalize per-sample min/max ----
__global__ void k_mmfin(const float* __restrict__ pmm, float* __restrict__ mnmx) {
  int b = threadIdx.x;
  if (b < NB) {
    float mn = pmm[(b * 16) * 2], mx = pmm[(b * 16) * 2 + 1];
    for (int t = 1; t < 16; ++t) {
      mn = fminf(mn, pmm[(b * 16 + t) * 2]);
      mx = fmaxf(mx, pmm[(b * 16 + t) * 2 + 1]);
    }
    mnmx[b * 2] = mn; mnmx[b * 2 + 1] = mx;
  }
}

// ---- K5a: normalized v, conv13 (zero-padded) -> raw scores sv ----
__global__ void k_score(const float* __restrict__ y, const float* __restrict__ mnmx,
                        const float* __restrict__ w, float* __restrict__ sv) {
  int blk = blockIdx.x; int b = blk >> 4, tile = blk & 15;
  int tid = threadIdx.x;
  __shared__ float vh[1024 + 2 * APAD];
  __shared__ float wl[ATT_K];
  float mn = mnmx[b * 2], inv = 1.f / (mnmx[b * 2 + 1] - mn);
  if (tid < ATT_K) wl[tid] = w[tid];
  int base = tile * 1024;
  for (int i = tid; i < 1024 + 2 * APAD; i += 256) {
    int j = base - APAD + i;
    vh[i] = (j >= 0 && j < LL) ? (y[b * LL + j] - mn) * inv : 0.f;
  }
  __syncthreads();
  int i0 = tid * 4;
  float4 o = {0.f, 0.f, 0.f, 0.f};
  #pragma unroll
  for (int k = 0; k < ATT_K; ++k) {
    float wk = wl[k];
    o.x += vh[i0 + k + 0] * wk;
    o.y += vh[i0 + k + 1] * wk;
    o.z += vh[i0 + k + 2] * wk;
    o.w += vh[i0 + k + 3] * wk;
  }
  *(float4*)(sv + b * LL + base + i0) = o;
}

// ---- K5b: per-sample exact top-8192 (radix select, ties -> lowest index), scatter sparse ----
__global__ void k_select(const float* __restrict__ sv, const float* __restrict__ y,
                         const float* __restrict__ mnmx, float* __restrict__ sp) {
  int b = blockIdx.x;
  int tid = threadIdx.x;
  const float* svb = sv + b * LL;
  __shared__ int red[4][3];
  __shared__ int scan[256];

  unsigned p = 0; int need = KLIM;
  for (int sh = 30; sh >= 0; sh -= 2) {
    unsigned himask = (sh == 30) ? 0u : (0xFFFFFFFFu << (sh + 2));
    int c3 = 0, c2 = 0, c1 = 0;
    #pragma unroll 4
    for (int i = 0; i < 16; ++i) {
      float4 f = *(const float4*)(svb + i * 1024 + tid * 4);
      unsigned kk;
      kk = fkey(f.x); if ((kk & himask) == p) { unsigned bk = (kk >> sh) & 3u; c3 += (bk == 3); c2 += (bk == 2); c1 += (bk == 1); }
      kk = fkey(f.y); if ((kk & himask) == p) { unsigned bk = (kk >> sh) & 3u; c3 += (bk == 3); c2 += (bk == 2); c1 += (bk == 1); }
      kk = fkey(f.z); if ((kk & himask) == p) { unsigned bk = (kk >> sh) & 3u; c3 += (bk == 3); c2 += (bk == 2); c1 += (bk == 1); }
      kk = fkey(f.w); if ((kk & himask) == p) { unsigned bk = (kk >> sh) & 3u; c3 += (bk == 3); c2 += (bk == 2); c1 += (bk == 1); }
    }
    #pragma unroll
    for (int m = 1; m < 64; m <<= 1) {
      c3 += __shfl_xor(c3, m); c2 += __shfl_xor(c2, m); c1 += __shfl_xor(c1, m);
    }
    if ((tid & 63) == 0) { red[tid >> 6][0] = c3; red[tid >> 6][1] = c2; red[tid >> 6][2] = c1; }
    __syncthreads();
    int C3 = red[0][0] + red[1][0] + red[2][0] + red[3][0];
    int C2 = red[0][1] + red[1][1] + red[2][1] + red[3][1];
    int C1 = red[0][2] + red[1][2] + red[2][2] + red[3][2];
    __syncthreads();
    if (C3 >= need)                { p |= 3u << sh; }
    else if (C3 + C2 >= need)      { p |= 2u << sh; need -= C3; }
    else if (C3 + C2 + C1 >= need) { p |= 1u << sh; need -= C3 + C2; }
    else                           { need -= C3 + C2 + C1; }
  }
  // p == key of the 8192nd largest; `need` of the == keys (lowest index first) are kept.
  int base = tid * 64;
  int cnt = 0;
  #pragma unroll 8
  for (int i = 0; i < 64; ++i) cnt += (fkey(svb[base + i]) == p);
  scan[tid] = cnt;
  __syncthreads();
  for (int off = 1; off < 256; off <<= 1) {
    int v = scan[tid];
    if (tid >= off) v += scan[tid - off];
    __syncthreads();
    scan[tid] = v;
    __syncthreads();
  }
  int rank = scan[tid] - cnt;  // exclusive prefix of equal-count by index
  float mn = mnmx[b * 2], inv = 1.f / (mnmx[b * 2 + 1] - mn);
  #pragma unroll 4
  for (int i = 0; i < 64; ++i) {
    float s = svb[base + i];
    unsigned kk = fkey(s);
    bool sel;
    if (kk > p) sel = true;
    else if (kk == p) { sel = (rank < need); rank++; }
    else sel = false;
    float out = 0.f;
    if (sel) {
      float vn = (y[b * LL + base + i] - mn) * inv;
      out = vn * (sigmoidf(s) + 1.f);
    }
    sp[b * LL + base + i] = out;
  }
}

// ---- K6: h[b,n] = b1[n] + sum_j sp[b,j]*W1[n,j] ; 4 rows/block, full K ----
__global__ __launch_bounds__(256) void k_gemm1(const float* __restrict__ W1, const float* __restrict__ b1,
                                               const float* __restrict__ sp, float* __restrict__ h) {
  int row0 = blockIdx.x * 4;
  int tid = threadIdx.x;
  float acc[4][8];
  #pragma unroll
  for (int r = 0; r < 4; ++r)
    #pragma unroll
    for (int bb = 0; bb < 8; ++bb) acc[r][bb] = 0.f;
  for (int it = 0; it < 16; ++it) {
    int j = it * 1024 + tid * 4;
    float4 s[8];
    #pragma unroll
    for (int bb = 0; bb < 8; ++bb) s[bb] = *(const float4*)(sp + bb * LL + j);
    #pragma unroll
    for (int r = 0; r < 4; ++r) {
      float4 w = *(const float4*)(W1 + (size_t)(row0 + r) * LL + j);
      #pragma unroll
      for (int bb = 0; bb < 8; ++bb)
        acc[r][bb] += w.x * s[bb].x + w.y * s[bb].y + w.z * s[bb].z + w.w * s[bb].w;
    }
  }
  __shared__ float part[4][32];
  int wave = tid >> 6;
  #pragma unroll
  for (int r = 0; r < 4; ++r)
    #pragma unroll
    for (int bb = 0; bb < 8; ++bb) {
      float v = acc[r][bb];
      #pragma unroll
      for (int m = 1; m < 64; m <<= 1) v += __shfl_xor(v, m);
      if ((tid & 63) == 0) part[wave][r * 8 + bb] = v;
    }
  __syncthreads();
  if (tid < 32) {
    int r = tid >> 3, bb = tid & 7;
    float v = part[0][tid] + part[1][tid] + part[2][tid] + part[3][tid];
    h[bb * N1 + row0 + r] = v + b1[row0 + r];
  }
}

// ---- K7: h2[b,m] = b2[m] + sum_n h[b,n]*W2[m,n] ; K=6000 ----
__global__ __launch_bounds__(256) void k_gemm2(const float* __restrict__ W2, const float* __restrict__ b2,
                                               const float* __restrict__ h, float* __restrict__ h2) {
  int row0 = blockIdx.x * 4;
  int tid = threadIdx.x;
  float acc[4][8];
  #pragma unroll
  for (int r = 0; r < 4; ++r)
    #pragma unroll
    for (int bb = 0; bb < 8; ++bb) acc[r][bb] = 0.f;
  for (int j = tid * 4; j < N1; j += 1024) {
    float4 s[8];
    #pragma unroll
    for (int bb = 0; bb < 8; ++bb) s[bb] = *(const float4*)(h + bb * N1 + j);
    #pragma unroll
    for (int r = 0; r < 4; ++r) {
      int row = row0 + r; if (row >= N2) row = N2 - 1;
      float4 w = *(const float4*)(W2 + (size_t)row * N1 + j);
      #pragma unroll
      for (int bb = 0; bb < 8; ++bb)
        acc[r][bb] += w.x * s[bb].x + w.y * s[bb].y + w.z * s[bb].z + w.w * s[bb].w;
    }
  }
  __shared__ float part[4][32];
  int wave = tid >> 6;
  #pragma unroll
  for (int r = 0; r < 4; ++r)
    #pragma unroll
    for (int bb = 0; bb < 8; ++bb) {
      float v = acc[r][bb];
      #pragma unroll
      for (int m = 1; m < 64; m <<= 1) v += __shfl_xor(v, m);
      if ((tid & 63) == 0) part[wave][r * 8 + bb] = v;
    }
  __syncthreads();
  if (tid < 32) {
    int r = tid >> 3, bb = tid & 7;
    int row = row0 + r;
    if (row < N2) {
      float v = part[0][tid] + part[1][tid] + part[2][tid] + part[3][tid];
      h2[bb * N2 + row] = v + b2[row];
    }
  }
}

// ---- K8: t[b,m] = sum_n h2[b,n]*Wc1[m,n] ; one block per (b,m) ----
__global__ void k_cls1(const float* __restrict__ h2, const float* __restrict__ Wc1,
                       float* __restrict__ t) {
  int bid = blockIdx.x; int b = bid >> 5, m = bid & 31;
  int tid = threadIdx.x;
  const float* hb = h2 + b * N2;
  const float* wm = Wc1 + m * N2;
  float s = 0.f;
  for (int j = tid; j < N2; j += 256) s += hb[j] * wm[j];
  #pragma unroll
  for (int mm = 1; mm < 64; mm <<= 1) s += __shfl_xor(s, mm);
  __shared__ float red[4];
  if ((tid & 63) == 0) red[tid >> 6] = s;
  __syncthreads();
  if (tid == 0) t[b * 32 + m] = red[0] + red[1] + red[2] + red[3];
}

// ---- K9: logits = t @ Wc2^T ; log_softmax ----
__global__ void k_final(const float* __restrict__ t, const float* __restrict__ Wc2,
                        float* __restrict__ out) {
  int b = threadIdx.x;
  if (b < NB) {
    float lg[NCLS];
    #pragma unroll
    for (int k = 0; k < NCLS; ++k) {
      float s = 0.f;
      #pragma unroll
      for (int m = 0; m < 32; ++m) s += t[b * 32 + m] * Wc2[k * 32 + m];
      lg[k] = s;
    }
    float mx = lg[0];
    #pragma unroll
    for (int k = 1; k < NCLS; ++k) mx = fmaxf(mx, lg[k]);
    float se = 0.f;
    #pragma unroll
    for (int k = 0; k < NCLS; ++k) se += expf(lg[k] - mx);
    float lse = logf(se);
    #pragma unroll
    for (int k = 0; k < NCLS; ++k) out[b * NCLS + k] = lg[k] - mx - lse;
  }
}

extern "C" void kernel_launch(void* const* d_in, const int* in_sizes, int n_in,
                              void* d_out, int out_size, void* d_ws, size_t ws_size,
                              hipStream_t stream) {
  const float* adj   = (const float*)d_in[0];
  const float* eca_w = (const float*)d_in[1];
  const float* att_w = (const float*)d_in[2];
  const float* W1    = (const float*)d_in[3];
  const float* b1    = (const float*)d_in[4];
  const float* W2    = (const float*)d_in[5];
  const float* b2    = (const float*)d_in[6];
  const float* Wc1   = (const float*)d_in[7];
  const float* Wc2   = (const float*)d_in[8];
  float* out = (float*)d_out;
  float* ws  = (float*)d_ws;

  float* pooled = ws;              // 240
  float* scale  = ws + 256;        // 240
  float* pmm    = ws + 512;        // 256
  float* mnmx   = ws + 768;        // 16
  float* y      = ws + 1024;       // 131072
  float* sv     = y  + NB * LL;    // 131072
  float* sp     = sv + NB * LL;    // 131072
  float* h      = sp + NB * LL;    // 48000
  float* h2     = h  + NB * N1;    // 39312
  float* tbuf   = h2 + NB * N2;    // 256

  k_pool  <<<NB * NCH, 256, 0, stream>>>(adj, pooled);
  k_eca   <<<1, 256, 0, stream>>>(pooled, eca_w, scale, out + NB * NCLS);
  k_wsum  <<<NB * 16, 256, 0, stream>>>(adj, scale, y, pmm);
  k_mmfin <<<1, 64, 0, stream>>>(pmm, mnmx);
  k_score <<<NB * 16, 256, 0, stream>>>(y, mnmx, att_w, sv);
  k_select<<<NB, 256, 0, stream>>>(sv, y, mnmx, sp);
  k_gemm1 <<<N1 / 4, 256, 0, stream>>>(W1, b1, sp, h);
  k_gemm2 <<<(N2 + 3) / 4, 256, 0, stream>>>(W2, b2, h, h2);
  k_cls1  <<<NB * 32, 256, 0, stream>>>(h2, Wc1, tbuf);
  k_final <<<1, 64, 0, stream>>>(tbuf, Wc2, out);
}

// Round 2
// 231.695 us; speedup vs baseline: 1.4458x; 1.4458x over previous
//
#include <hip/hip_runtime.h>
#include <math.h>

#define NB 8
#define NCH 30
#define LL 16384
#define N1 6000
#define N2 4914
#define NCLS 5
#define KLIM 8192
#define ATT_K 13

__device__ __forceinline__ unsigned fkey(float f) {
  unsigned u = __float_as_uint(f);
  unsigned m = (unsigned)(((int)u) >> 31) | 0x80000000u;
  return u ^ m;  // order-preserving float->uint
}
__device__ __forceinline__ float sigmoidf(float x) { return 1.f / (1.f + expf(-x)); }

// ---- K1: per-(b,c) mean pool over HxH = 16384 ----
__global__ void k_pool(const float* __restrict__ adj, float* __restrict__ pooled) {
  int bc = blockIdx.x;                       // 0..239
  const float* p = adj + (size_t)bc * LL;
  int tid = threadIdx.x;
  float s = 0.f;
  #pragma unroll
  for (int it = 0; it < LL / (256 * 4); ++it) {
    float4 v = *(const float4*)(p + it * 1024 + tid * 4);
    s += v.x + v.y + v.z + v.w;
  }
  #pragma unroll
  for (int m = 1; m < 64; m <<= 1) s += __shfl_xor(s, m);
  __shared__ float red[4];
  if ((tid & 63) == 0) red[tid >> 6] = s;
  __syncthreads();
  if (tid == 0) pooled[bc] = (red[0] + red[1] + red[2] + red[3]) * (1.f / (float)LL);
}

// ---- K2: ECA conv(k=3,pad=1) + sigmoid; writes scale and band_score output ----
__global__ void k_eca(const float* __restrict__ pooled, const float* __restrict__ w,
                      float* __restrict__ scale, float* __restrict__ band_out) {
  int t = threadIdx.x;
  if (t < NB * NCH) {
    int b = t / NCH, c = t % NCH;
    const float* p = pooled + b * NCH;
    float s = w[1] * p[c];
    if (c > 0)       s += w[0] * p[c - 1];
    if (c < NCH - 1) s += w[2] * p[c + 1];
    float sc = sigmoidf(s);
    scale[t] = sc;
    band_out[t] = sc;
  }
}

// ---- K3: y[b,j] = sum_c adj[b,c,j]*scale[b,c]; per-block partial min/max ----
__global__ void k_wsum(const float* __restrict__ adj, const float* __restrict__ scale,
                       float* __restrict__ y, float* __restrict__ pmm) {
  int blk = blockIdx.x;                       // b*16 + tile
  int b = blk >> 4, tile = blk & 15;
  int tid = threadIdx.x;
  __shared__ float sc[NCH];
  if (tid < NCH) sc[tid] = scale[b * NCH + tid];
  __syncthreads();
  int j = tile * 1024 + tid * 4;
  const float* base = adj + (size_t)b * NCH * LL + j;
  float4 acc = {0.f, 0.f, 0.f, 0.f};
  #pragma unroll
  for (int c = 0; c < NCH; ++c) {
    float4 v = *(const float4*)(base + (size_t)c * LL);
    float s = sc[c];
    acc.x += v.x * s; acc.y += v.y * s; acc.z += v.z * s; acc.w += v.w * s;
  }
  *(float4*)(y + b * LL + j) = acc;
  float mn = fminf(fminf(acc.x, acc.y), fminf(acc.z, acc.w));
  float mx = fmaxf(fmaxf(acc.x, acc.y), fmaxf(acc.z, acc.w));
  #pragma unroll
  for (int m = 1; m < 64; m <<= 1) {
    mn = fminf(mn, __shfl_xor(mn, m));
    mx = fmaxf(mx, __shfl_xor(mx, m));
  }
  __shared__ float wmn[4], wmx[4];
  if ((tid & 63) == 0) { wmn[tid >> 6] = mn; wmx[tid >> 6] = mx; }
  __syncthreads();
  if (tid == 0) {
    mn = fminf(fminf(wmn[0], wmn[1]), fminf(wmn[2], wmn[3]));
    mx = fmaxf(fmaxf(wmx[0], wmx[1]), fmaxf(wmx[2], wmx[3]));
    pmm[blk * 2 + 0] = mn; pmm[blk * 2 + 1] = mx;
  }
}

// ---- K4 (fused): normalize -> conv13 -> exact top-8192 select -> scatter sparse ----
// One block per sample, 1024 threads. y tile in padded LDS; conv scores, keys,
// and v values live in registers; radix passes are VALU-only + tiny LDS reduce.
__global__ __launch_bounds__(1024) void k_selfuse(const float* __restrict__ y,
                                                  const float* __restrict__ pmm,
                                                  const float* __restrict__ w,
                                                  float* __restrict__ sp) {
  int b = blockIdx.x;
  int tid = threadIdx.x;
  int wave = tid >> 6;
  extern __shared__ float vsh[];            // 16896 floats, idx(j) = j + (j>>5)
  __shared__ float wl[ATT_K];
  __shared__ int red[16][16][4];            // [pass][wave][channel]
  __shared__ int wtot[16];
  if (tid < ATT_K) wl[tid] = w[tid];

  // per-sample min/max from the 16 partials
  float mn = pmm[b * 32], mx = pmm[b * 32 + 1];
  #pragma unroll
  for (int t = 1; t < 16; ++t) {
    mn = fminf(mn, pmm[b * 32 + t * 2]);
    mx = fmaxf(mx, pmm[b * 32 + t * 2 + 1]);
  }
  float inv = 1.f / (mx - mn);

  // load + normalize y into padded LDS
  const float* yb = y + b * LL;
  #pragma unroll
  for (int c = 0; c < 4; ++c) {
    int i = c * 4096 + tid * 4;
    float4 t4 = *(const float4*)(yb + i);
    int p0 = i + (i >> 5);                  // pad offset constant across the 4
    vsh[p0 + 0] = (t4.x - mn) * inv;
    vsh[p0 + 1] = (t4.y - mn) * inv;
    vsh[p0 + 2] = (t4.z - mn) * inv;
    vsh[p0 + 3] = (t4.w - mn) * inv;
  }
  __syncthreads();

  // conv13 for 16 contiguous elements per thread; keep v, s, keys in regs
  int e = tid * 16;
  float v28[28];
  #pragma unroll
  for (int i = 0; i < 28; ++i) {
    int j = e - 6 + i;
    v28[i] = (j >= 0 && j < LL) ? vsh[j + (j >> 5)] : 0.f;
  }
  float s[16], v[16];
  unsigned kk[16];
  #pragma unroll
  for (int i = 0; i < 16; ++i) {
    float acc = 0.f;
    #pragma unroll
    for (int k = 0; k < ATT_K; ++k) acc += v28[i + k] * wl[k];
    s[i] = acc;
    v[i] = v28[i + 6];
    kk[i] = fkey(acc);
  }

  // 16 x 2-bit radix select for the KLIM-th largest key
  unsigned p = 0; int need = KLIM;
  for (int pass = 0; pass < 16; ++pass) {
    int sh = 30 - pass * 2;
    unsigned himask = (pass == 0) ? 0u : (0xFFFFFFFFu << (sh + 2));
    int c3 = 0, c2 = 0, c1 = 0;
    #pragma unroll
    for (int i = 0; i < 16; ++i) {
      unsigned k2 = kk[i];
      if ((k2 & himask) == p) {
        unsigned bk = (k2 >> sh) & 3u;
        c3 += (bk == 3); c2 += (bk == 2); c1 += (bk == 1);
      }
    }
    #pragma unroll
    for (int m = 1; m < 64; m <<= 1) {
      c3 += __shfl_xor(c3, m); c2 += __shfl_xor(c2, m); c1 += __shfl_xor(c1, m);
    }
    if ((tid & 63) == 0) { red[pass][wave][0] = c3; red[pass][wave][1] = c2; red[pass][wave][2] = c1; }
    __syncthreads();
    int C3 = 0, C2 = 0, C1 = 0;
    #pragma unroll
    for (int t = 0; t < 16; ++t) { C3 += red[pass][t][0]; C2 += red[pass][t][1]; C1 += red[pass][t][2]; }
    if (C3 >= need)                { p |= 3u << sh; }
    else if (C3 + C2 >= need)      { p |= 2u << sh; need -= C3; }
    else if (C3 + C2 + C1 >= need) { p |= 1u << sh; need -= C3 + C2; }
    else                           { need -= C3 + C2 + C1; }
  }

  // rank equal keys in global index order (thread-contiguous layout)
  int cnt = 0;
  #pragma unroll
  for (int i = 0; i < 16; ++i) cnt += (kk[i] == p);
  int pre = cnt;
  #pragma unroll
  for (int m = 1; m < 64; m <<= 1) {
    int t = __shfl_up(pre, m);
    if ((tid & 63) >= m) pre += t;
  }
  if ((tid & 63) == 63) wtot[wave] = pre;   // wave total
  __syncthreads();
  int base = 0;
  for (int t = 0; t < 16; ++t) if (t < wave) base += wtot[t];
  int rank = base + pre - cnt;              // exclusive prefix in index order

  float* spb = sp + b * LL;
  #pragma unroll
  for (int i = 0; i < 16; ++i) {
    bool sel;
    if (kk[i] > p) sel = true;
    else if (kk[i] == p) { sel = (rank < need); rank++; }
    else sel = false;
    spb[e + i] = sel ? v[i] * (sigmoidf(s[i]) + 1.f) : 0.f;
  }
}

// ---- K6: h = sp @ W1^T + b1 ; 8 rows/block, LDS-staged sp, wave owns 2 rows ----
__global__ __launch_bounds__(256) void k_gemm1(const float* __restrict__ W1, const float* __restrict__ b1,
                                               const float* __restrict__ sp, float* __restrict__ h) {
  int row0 = blockIdx.x * 8;
  int tid = threadIdx.x;
  int wave = tid >> 6, lane = tid & 63;
  int r0 = row0 + wave * 2;
  __shared__ float sps[8][1024];
  float acc[2][8];
  #pragma unroll
  for (int r = 0; r < 2; ++r)
    #pragma unroll
    for (int bb = 0; bb < 8; ++bb) acc[r][bb] = 0.f;

  for (int it = 0; it < 16; ++it) {
    int j0 = it * 1024;
    #pragma unroll
    for (int c = 0; c < 8; ++c)
      *(float4*)&sps[c][tid * 4] = *(const float4*)(sp + (size_t)c * LL + j0 + tid * 4);
    __syncthreads();
    #pragma unroll
    for (int sub = 0; sub < 4; ++sub) {
      int k0 = sub * 256 + lane * 4;
      float4 w0 = *(const float4*)(W1 + (size_t)r0 * LL + j0 + k0);
      float4 w1 = *(const float4*)(W1 + (size_t)(r0 + 1) * LL + j0 + k0);
      #pragma unroll
      for (int bb = 0; bb < 8; ++bb) {
        float4 s4 = *(const float4*)&sps[bb][k0];
        acc[0][bb] += w0.x * s4.x + w0.y * s4.y + w0.z * s4.z + w0.w * s4.w;
        acc[1][bb] += w1.x * s4.x + w1.y * s4.y + w1.z * s4.z + w1.w * s4.w;
      }
    }
    __syncthreads();
  }
  #pragma unroll
  for (int r = 0; r < 2; ++r)
    #pragma unroll
    for (int bb = 0; bb < 8; ++bb) {
      float vv = acc[r][bb];
      #pragma unroll
      for (int m = 1; m < 64; m <<= 1) vv += __shfl_xor(vv, m);
      if (lane == 0) h[bb * N1 + r0 + r] = vv + b1[r0 + r];
    }
}

// ---- K7: h2 = h @ W2^T + b2 ; same structure, K=6000 with tail guard ----
__global__ __launch_bounds__(256) void k_gemm2(const float* __restrict__ W2, const float* __restrict__ b2,
                                               const float* __restrict__ h, float* __restrict__ h2) {
  int row0 = blockIdx.x * 8;
  int tid = threadIdx.x;
  int wave = tid >> 6, lane = tid & 63;
  int r0 = row0 + wave * 2;
  int rr0 = r0 < N2 ? r0 : N2 - 1;
  int rr1 = (r0 + 1) < N2 ? (r0 + 1) : N2 - 1;
  __shared__ float hs[8][1024];
  float acc[2][8];
  #pragma unroll
  for (int r = 0; r < 2; ++r)
    #pragma unroll
    for (int bb = 0; bb < 8; ++bb) acc[r][bb] = 0.f;

  for (int it = 0; it < 6; ++it) {
    int j0 = it * 1024;
    #pragma unroll
    for (int c = 0; c < 8; ++c) {
      int j = j0 + tid * 4;
      float4 t4 = {0.f, 0.f, 0.f, 0.f};
      if (j < N1) t4 = *(const float4*)(h + (size_t)c * N1 + j);
      *(float4*)&hs[c][tid * 4] = t4;
    }
    __syncthreads();
    #pragma unroll
    for (int sub = 0; sub < 4; ++sub) {
      int k0 = sub * 256 + lane * 4;
      int j = j0 + k0;
      float4 w0 = {0.f, 0.f, 0.f, 0.f}, w1 = {0.f, 0.f, 0.f, 0.f};
      if (j < N1) {
        w0 = *(const float4*)(W2 + (size_t)rr0 * N1 + j);
        w1 = *(const float4*)(W2 + (size_t)rr1 * N1 + j);
      }
      #pragma unroll
      for (int bb = 0; bb < 8; ++bb) {
        float4 s4 = *(const float4*)&hs[bb][k0];
        acc[0][bb] += w0.x * s4.x + w0.y * s4.y + w0.z * s4.z + w0.w * s4.w;
        acc[1][bb] += w1.x * s4.x + w1.y * s4.y + w1.z * s4.z + w1.w * s4.w;
      }
    }
    __syncthreads();
  }
  #pragma unroll
  for (int r = 0; r < 2; ++r)
    #pragma unroll
    for (int bb = 0; bb < 8; ++bb) {
      float vv = acc[r][bb];
      #pragma unroll
      for (int m = 1; m < 64; m <<= 1) vv += __shfl_xor(vv, m);
      int row = r0 + r;
      if (lane == 0 && row < N2) h2[bb * N2 + row] = vv + b2[row];
    }
}

// ---- K8: t[b,m] = sum_n h2[b,n]*Wc1[m,n] ; one block per (b,m) ----
__global__ void k_cls1(const float* __restrict__ h2, const float* __restrict__ Wc1,
                       float* __restrict__ t) {
  int bid = blockIdx.x; int b = bid >> 5, m = bid & 31;
  int tid = threadIdx.x;
  const float* hb = h2 + b * N2;
  const float* wm = Wc1 + m * N2;
  float s = 0.f;
  for (int j = tid; j < N2; j += 256) s += hb[j] * wm[j];
  #pragma unroll
  for (int mm = 1; mm < 64; mm <<= 1) s += __shfl_xor(s, mm);
  __shared__ float red[4];
  if ((tid & 63) == 0) red[tid >> 6] = s;
  __syncthreads();
  if (tid == 0) t[b * 32 + m] = red[0] + red[1] + red[2] + red[3];
}

// ---- K9: logits = t @ Wc2^T ; log_softmax ----
__global__ void k_final(const float* __restrict__ t, const float* __restrict__ Wc2,
                        float* __restrict__ out) {
  int b = threadIdx.x;
  if (b < NB) {
    float lg[NCLS];
    #pragma unroll
    for (int k = 0; k < NCLS; ++k) {
      float s = 0.f;
      #pragma unroll
      for (int m = 0; m < 32; ++m) s += t[b * 32 + m] * Wc2[k * 32 + m];
      lg[k] = s;
    }
    float mx = lg[0];
    #pragma unroll
    for (int k = 1; k < NCLS; ++k) mx = fmaxf(mx, lg[k]);
    float se = 0.f;
    #pragma unroll
    for (int k = 0; k < NCLS; ++k) se += expf(lg[k] - mx);
    float lse = logf(se);
    #pragma unroll
    for (int k = 0; k < NCLS; ++k) out[b * NCLS + k] = lg[k] - mx - lse;
  }
}

extern "C" void kernel_launch(void* const* d_in, const int* in_sizes, int n_in,
                              void* d_out, int out_size, void* d_ws, size_t ws_size,
                              hipStream_t stream) {
  const float* adj   = (const float*)d_in[0];
  const float* eca_w = (const float*)d_in[1];
  const float* att_w = (const float*)d_in[2];
  const float* W1    = (const float*)d_in[3];
  const float* b1    = (const float*)d_in[4];
  const float* W2    = (const float*)d_in[5];
  const float* b2    = (const float*)d_in[6];
  const float* Wc1   = (const float*)d_in[7];
  const float* Wc2   = (const float*)d_in[8];
  float* out = (float*)d_out;
  float* ws  = (float*)d_ws;

  float* pooled = ws;              // 240
  float* scale  = ws + 256;        // 240
  float* pmm    = ws + 512;        // 256
  float* y      = ws + 1024;       // 131072
  float* sp     = y  + NB * LL;    // 131072
  float* h      = sp + NB * LL;    // 48000
  float* h2     = h  + NB * N1;    // 39312
  float* tbuf   = h2 + NB * N2;    // 256

  k_pool   <<<NB * NCH, 256, 0, stream>>>(adj, pooled);
  k_eca    <<<1, 256, 0, stream>>>(pooled, eca_w, scale, out + NB * NCLS);
  k_wsum   <<<NB * 16, 256, 0, stream>>>(adj, scale, y, pmm);
  k_selfuse<<<NB, 1024, 16896 * sizeof(float), stream>>>(y, pmm, att_w, sp);
  k_gemm1  <<<N1 / 8, 256, 0, stream>>>(W1, b1, sp, h);
  k_gemm2  <<<(N2 + 7) / 8, 256, 0, stream>>>(W2, b2, h, h2);
  k_cls1   <<<NB * 32, 256, 0, stream>>>(h2, Wc1, tbuf);
  k_final  <<<1, 64, 0, stream>>>(tbuf, Wc2, out);
}